// Round 5
// baseline (86.162 us; speedup 1.0000x reference)
//
#include <hip/hip_runtime.h>
#include <math.h>

// Base = R15 (82.1us; per-task math bitwise = R11). R16 change: WAVE-AUTONOMOUS
// execution -- zero __syncthreads in the hot path. R13/R15 falsified capacity/
// churn theories; remaining suspect is barrier convoying (4-wave rendezvous x
// unequal per-wave work, all blocks phase-locked). Now each WAVE owns one image
// end-to-end with a private LDS slice; cross-phase LDS visibility within one
// wave needs only s_waitcnt lgkmcnt(0) (asm + memory clobber), not a barrier.
//   Block = 192 thr = 3 waves, LDS = 3*(1008+288)f2 + trig2 520f2 = 34.4KB
//   -> 4 blocks/CU = 12 independent convoy-free waves/CU.
//   P1: 4 in-wave rounds (pos = lane+64r < 196), per-position body = R11.
//   P2: R11's 96-task (oi,ojg,ocp,hf) map as 2 in-wave rounds (task=lane+64r);
//       same 128 ds_read_b128/image; shfl_xor(,1) pair-reduce intact.
//   P3: 5 full in-wave rounds of R11's (n,s32) body (320 = 5*64).
//   One barrier per block lifetime (trig2 staging), before any wave-work.
// Bitwise identical outputs (fp add commutativity covers hf-order).
//
// d_ws trig layout (float2 = {cos,sin}):
//   [0,2880)    fft:   [n*288 + k]            (transposed ff_w trig)
//   [2880,3400) trig2: [ocp*130 + e*2 + (oc&1)], e = ch*16+ki*4+kj (pad 130)
//   [3400,3416) trig1: [oc*4 + e], e = a*2+c
#define FFT_OFF 0
#define W2_OFF 2880
#define W1_OFF 3400

__global__ void precompute_trig(const float* __restrict__ w1,
                                const float* __restrict__ w2,
                                const float* __restrict__ ff,
                                float2* __restrict__ ws) {
    int idx = blockIdx.x * blockDim.x + threadIdx.x;
    if (idx < 2880) {
        int k = idx / 10, n = idx % 10;
        float s, c; sincosf(ff[idx], &s, &c);
        ws[FFT_OFF + n * 288 + k] = make_float2(c, s);
    } else if (idx < 3392) {
        int i = idx - 2880;                  // i = oc*64 + e
        int oc = i >> 6, e = i & 63;
        float s, c; sincosf(w2[i], &s, &c);
        ws[W2_OFF + (oc >> 1) * 130 + e * 2 + (oc & 1)] = make_float2(c, s);
    } else if (idx < 3408) {
        int i = idx - 3392;
        float s, c; sincosf(w1[i], &s, &c);
        ws[W1_OFF + i] = make_float2(c, s);
    }
}

// One conv1 output position: 4 sincos + 4 oc x (16 fma + rsqrt).
// Bitwise identical to R11's per-position phase-1 body.
__device__ __forceinline__ void conv1_pos(float2 r0, float2 r1,
                                          const float2* __restrict__ w1t,
                                          float2* __restrict__ sc1,
                                          int pi, int pj) {
    float sx[4], cx[4];
    __sincosf(r0.x, &sx[0], &cx[0]);
    __sincosf(r0.y, &sx[1], &cx[1]);
    __sincosf(r1.x, &sx[2], &cx[2]);
    __sincosf(r1.y, &sx[3], &cx[3]);
    #pragma unroll
    for (int oc = 0; oc < 4; oc++) {
        float4 wa = *(const float4*)(w1t + oc * 4);      // taps e0,e1 (uniform)
        float4 wb = *(const float4*)(w1t + oc * 4 + 2);  // taps e2,e3 (uniform)
        float Y = 0.f, X = 0.f;
        Y = fmaf(sx[0], wa.x, fmaf(-cx[0], wa.y, Y));
        X = fmaf(cx[0], wa.x, fmaf( sx[0], wa.y, X));
        Y = fmaf(sx[1], wa.z, fmaf(-cx[1], wa.w, Y));
        X = fmaf(cx[1], wa.z, fmaf( sx[1], wa.w, X));
        Y = fmaf(sx[2], wb.x, fmaf(-cx[2], wb.y, Y));
        X = fmaf(cx[2], wb.x, fmaf( sx[2], wb.y, X));
        Y = fmaf(sx[3], wb.z, fmaf(-cx[3], wb.w, Y));
        X = fmaf(cx[3], wb.z, fmaf( sx[3], wb.w, X));
        float inv = rsqrtf(fmaxf(fmaf(X, X, Y * Y), 1e-30f));
        sc1[oc * 252 + pi * 18 + pj] = make_float2(Y * inv, X * inv);
    }
}

// 192 threads = 3 waves; 1 image PER WAVE; grid = ceil(B/3).
// LDS: trig2 520f2 + 3*sc1 1008f2 + 3*sc2 288f2 = 34.4KB -> 4 blocks/CU.
__global__ __launch_bounds__(192, 4) void ringnn_kernel(
    const float* __restrict__ x,
    const float2* __restrict__ ws,
    float* __restrict__ out,
    int nImg)
{
    __shared__ __align__(16) float2 trig2[520];
    __shared__ __align__(16) float2 sc1s[3 * 1008]; // wave*1008 + ch*252 + row*18 + col
    __shared__ __align__(16) float2 sc2s[3 * 288];  // wave*288 + p*8 + oc
    const int tid = threadIdx.x;
    const int wave = tid >> 6, lane = tid & 63;
    const int img = blockIdx.x * 3 + wave;
    const float2* __restrict__ fft = ws + FFT_OFF;
    const float2* __restrict__ w1t = ws + W1_OFF;
    const bool live = (img < nImg);

    // ---- hoisted x loads for all 4 P1 rounds (before the staging barrier) ----
    const float* xp = x + (size_t)img * 784;
    float2 xa[4], xb[4];
    #pragma unroll
    for (int r = 0; r < 4; r++) {
        int pos = lane + (r << 6);
        xa[r] = make_float2(0.f, 0.f); xb[r] = make_float2(0.f, 0.f);
        if (live && pos < 196) {
            int pi = pos / 14, pj = pos % 14;
            xa[r] = *(const float2*)(xp + (2 * pi) * 28 + 2 * pj);
            xb[r] = *(const float2*)(xp + (2 * pi + 1) * 28 + 2 * pj);
        }
    }

    // ---- stage trig2 (block-shared, read-only): the ONLY barrier ----
    for (int i = tid; i < 260; i += 192)
        ((float4*)trig2)[i] = ((const float4*)(ws + W2_OFF))[i];
    __syncthreads();
    if (!live) return;

    float2* __restrict__ sc1 = sc1s + wave * 1008;
    float2* __restrict__ sc2 = sc2s + wave * 288;

    // ---- phase 1: ring conv1, 196 positions in 4 in-wave rounds ----
    #pragma unroll
    for (int r = 0; r < 4; r++) {
        int pos = lane + (r << 6);
        if (pos < 196) conv1_pos(xa[r], xb[r], w1t, sc1, pos / 14, pos % 14);
    }
    // wave-private LDS: drain writes; no barrier needed (same-wave visibility)
    asm volatile("s_waitcnt lgkmcnt(0)" ::: "memory");

    // ---- phase 2: ring conv2; R11's 96-task map as 2 in-wave rounds ----
    #pragma unroll
    for (int rr = 0; rr < 2; rr++) {
        int task = lane + (rr << 6);
        if (task < 96) {
            int oi = task >> 4, ojg = (task >> 3) & 1, ocp = (task >> 1) & 3, hf = task & 1;
            const float2* wbp = trig2 + ocp * 130;
            float aY[3][2] = {{0.f,0.f},{0.f,0.f},{0.f,0.f}};
            float aX[3][2] = {{0.f,0.f},{0.f,0.f},{0.f,0.f}};
            #pragma unroll
            for (int ch = 0; ch < 4; ch++) {
                #pragma unroll
                for (int kk = 0; kk < 2; kk++) {
                    int ki = hf * 2 + kk;
                    int base = ch * 252 + (oi * 2 + ki) * 18 + ojg * 6;
                    float4 f0 = *(const float4*)(sc1 + base);
                    float4 f1 = *(const float4*)(sc1 + base + 2);
                    float4 f2 = *(const float4*)(sc1 + base + 4);
                    float4 f3 = *(const float4*)(sc1 + base + 6);
                    float ss[8] = {f0.x,f0.z,f1.x,f1.z,f2.x,f2.z,f3.x,f3.z};
                    float cc[8] = {f0.y,f0.w,f1.y,f1.w,f2.y,f2.w,f3.y,f3.w};
                    int e0 = ch * 16 + ki * 4;
                    #pragma unroll
                    for (int kj = 0; kj < 4; kj++) {
                        float4 wv = *(const float4*)(wbp + (e0 + kj) * 2); // (c0,s0,c1,s1)
                        #pragma unroll
                        for (int ojl = 0; ojl < 3; ojl++) {
                            float s = ss[ojl * 2 + kj], c = cc[ojl * 2 + kj];
                            aY[ojl][0] = fmaf(s, wv.x, fmaf(-c, wv.y, aY[ojl][0]));
                            aX[ojl][0] = fmaf(c, wv.x, fmaf( s, wv.y, aX[ojl][0]));
                            aY[ojl][1] = fmaf(s, wv.z, fmaf(-c, wv.w, aY[ojl][1]));
                            aX[ojl][1] = fmaf(c, wv.z, fmaf( s, wv.w, aX[ojl][1]));
                        }
                    }
                }
            }
            // even/odd lane pairs within the wave; identical to R11.
            #pragma unroll
            for (int ojl = 0; ojl < 3; ojl++) {
                float y0 = aY[ojl][0]; y0 += __shfl_xor(y0, 1);
                float y1 = aY[ojl][1]; y1 += __shfl_xor(y1, 1);
                float x0 = aX[ojl][0]; x0 += __shfl_xor(x0, 1);
                float x1 = aX[ojl][1]; x1 += __shfl_xor(x1, 1);
                float Y = hf ? y1 : y0;
                float X = hf ? x1 : x0;
                float inv = rsqrtf(fmaxf(fmaf(X, X, Y * Y), 1e-30f));
                int p = oi * 6 + ojg * 3 + ojl;
                sc2[p * 8 + ocp * 2 + hf] = make_float2(Y * inv, X * inv);
            }
        }
    }
    asm volatile("s_waitcnt lgkmcnt(0)" ::: "memory");

    // ---- phase 3: ring feed-forward; 320 tasks = 5 full in-wave rounds ----
    #pragma unroll
    for (int rr = 0; rr < 5; rr++) {
        int task = lane + (rr << 6);          // < 320, all lanes active
        int n = task >> 5, s = task & 31;
        const float2* wn = fft + n * 288;
        float Y = 0.f, X = 0.f;
        #pragma unroll
        for (int i = 0; i < 9; i++) {
            int k = i * 32 + s;
            float2 sc = sc2[k];
            float2 w = wn[k];
            Y = fmaf(sc.x, w.x, fmaf(-sc.y, w.y, Y));
            X = fmaf(sc.y, w.x, fmaf( sc.x, w.y, X));
        }
        #pragma unroll
        for (int off = 16; off > 0; off >>= 1) {
            Y += __shfl_down(Y, off, 32);
            X += __shfl_down(X, off, 32);
        }
        if (s == 0) {
            out[(size_t)img * 10 + n] =
                Y * rsqrtf(fmaxf(fmaf(X, X, Y * Y), 1e-30f));
        }
    }
}

extern "C" void kernel_launch(void* const* d_in, const int* in_sizes, int n_in,
                              void* d_out, int out_size, void* d_ws, size_t ws_size,
                              hipStream_t stream) {
    const float* x  = (const float*)d_in[0];
    const float* w1 = (const float*)d_in[1];
    const float* w2 = (const float*)d_in[2];
    const float* ff = (const float*)d_in[3];
    float* out = (float*)d_out;
    const int B = in_sizes[0] / 784;   // 4096

    float2* ws = (float2*)d_ws;
    precompute_trig<<<14, 256, 0, stream>>>(w1, w2, ff, ws);
    ringnn_kernel<<<(B + 2) / 3, 192, 0, stream>>>(x, ws, out, B);
}